// Round 1
// baseline (995.337 us; speedup 1.0000x reference)
//
#include <hip/hip_runtime.h>
#include <math.h>

#define BB 8
#define TT 256
#define UU 64
#define U1 65
#define VV 1024

// ---------------------------------------------------------------------------
// Kernel 1: per (b,t,u) row of 1024 logits, compute logsumexp and emit
//   lp_blank[b,t,u] = logits[b,t,u,0]      - lse
//   lp_label[b,t,u] = logits[b,t,u,y[b,u]] - lse   (u < UU only)
// One wave (64 lanes) per row; 4 coalesced float4 loads per lane.
// ---------------------------------------------------------------------------
__global__ __launch_bounds__(256) void k_rowsoftmax(
    const float* __restrict__ logits,
    const int* __restrict__ y,
    float* __restrict__ lp_blank,
    float* __restrict__ lp_label)
{
    const int lane = threadIdx.x & 63;
    const int r = (blockIdx.x * blockDim.x + threadIdx.x) >> 6;   // row id
    const int b   = r / (TT * U1);
    const int rem = r - b * (TT * U1);
    const int t   = rem / U1;
    const int u   = rem - t * U1;

    const float* row = logits + (size_t)r * VV;

    // Early, independent label-logit load (lane 0 only; row is L1/L2-hot later)
    float labv = 0.f;
    if (lane == 0 && u < UU) {
        int yidx = y[b * UU + u];
        labv = row[yidx];
    }

    // Interleaved coalesced loads: slot s covers elements [4s, 4s+3].
    const float4* row4 = (const float4*)row;
    float4 x0 = row4[lane];
    float4 x1 = row4[lane + 64];
    float4 x2 = row4[lane + 128];
    float4 x3 = row4[lane + 192];

    // Pass 1: max
    float m = fmaxf(fmaxf(fmaxf(x0.x, x0.y), fmaxf(x0.z, x0.w)),
                    fmaxf(fmaxf(x1.x, x1.y), fmaxf(x1.z, x1.w)));
    m = fmaxf(m, fmaxf(fmaxf(fmaxf(x2.x, x2.y), fmaxf(x2.z, x2.w)),
                       fmaxf(fmaxf(x3.x, x3.y), fmaxf(x3.z, x3.w))));
    #pragma unroll
    for (int off = 32; off; off >>= 1)
        m = fmaxf(m, __shfl_xor(m, off));

    // Pass 2: sum of exp(x - m)
    float s = __expf(x0.x - m) + __expf(x0.y - m) + __expf(x0.z - m) + __expf(x0.w - m)
            + __expf(x1.x - m) + __expf(x1.y - m) + __expf(x1.z - m) + __expf(x1.w - m)
            + __expf(x2.x - m) + __expf(x2.y - m) + __expf(x2.z - m) + __expf(x2.w - m)
            + __expf(x3.x - m) + __expf(x3.y - m) + __expf(x3.z - m) + __expf(x3.w - m);
    #pragma unroll
    for (int off = 32; off; off >>= 1)
        s += __shfl_xor(s, off);

    const float lse = m + __logf(s);

    if (lane == 0) {
        lp_blank[r] = x0.x - lse;                      // element 0 lives in lane0.x0.x
        if (u < UU)
            lp_label[(b * TT + t) * UU + u] = labv - lse;
    }
}

// ---------------------------------------------------------------------------
// Kernel 2: anti-diagonal wavefront DP, one wave per batch (8 waves, 1 block).
//   alpha[t][0] = alpha[t-1][0] + blank[t-1][0]                    (lane0 carry)
//   alpha[t][u] = logaddexp(alpha[t-1][u] + blank[t-1][u],
//                           alpha[t][u-1] + label[t][u-1])          u in [1,64]
// Lane l handles column u = l+1. Left neighbor via __shfl_up(cur, 1).
// ---------------------------------------------------------------------------
__device__ __forceinline__ float logaddexpf_(float a, float b) {
    float m = fmaxf(a, b);
    float d = fabsf(a - b);
    return m + log1pf(__expf(-d));
}

__global__ __launch_bounds__(512) void k_dp(
    const float* __restrict__ lp_blank,
    const float* __restrict__ lp_label,
    const int* __restrict__ logit_lens,
    const int* __restrict__ y_lens,
    float* __restrict__ out)
{
    __shared__ float sLL[BB];
    const int lane = threadIdx.x & 63;
    const int b    = threadIdx.x >> 6;

    const float* pb = lp_blank + b * TT * U1;   // [T][65]
    const float* pl = lp_label + b * TT * UU;   // [T][64]

    const int t_idx = logit_lens[b] - 1;        // in [127,255]
    const int u_idx = y_lens[b];                // in [32,64]
    const int u = lane + 1;

    // alpha0[u] = inclusive prefix sum of lp_label[b][0][0..lane]
    float cur = pl[lane];
    #pragma unroll
    for (int off = 1; off < 64; off <<= 1) {
        float tv = __shfl_up(cur, off);
        if (lane >= off) cur += tv;
    }

    float a0 = 0.f;                              // lane0: alpha[k][0] running value
    const float fin_blank = pb[t_idx * U1 + u_idx];
    float ll = 0.f;

    // Prefetch for d = 2
    int tc = 2 - u;  tc = tc < 1 ? 1 : tc;       // clamp (upper never hit at d=2)
    float blank_v = pb[(tc - 1) * U1 + u];
    float lab_v   = pl[tc * UU + lane];
    float blank0  = pb[0];                       // blank[d-2=0][0]

    for (int d = 2; d <= (TT - 1) + UU; ++d) {   // 318 diagonals
        const int t = d - u;

        // Prefetch d+1 (addresses independent of recurrence)
        int tn = d + 1 - u;
        tn = tn < 1 ? 1 : (tn > TT - 1 ? TT - 1 : tn);
        const float nblank  = pb[(tn - 1) * U1 + u];
        const float nlab    = pl[tn * UU + lane];
        const int   t0n     = (d - 1) < (TT - 1) ? (d - 1) : (TT - 1);
        const float nblank0 = pb[t0n * U1];

        // u=0 column carry: a0 becomes alpha[d-1][0]
        a0 += blank0;

        float left = __shfl_up(cur, 1);
        if (lane == 0) left = a0;

        if (t >= 1 && t <= TT - 1)
            cur = logaddexpf_(cur + blank_v, left + lab_v);

        if (t == t_idx && lane == u_idx - 1)
            ll = cur + fin_blank;

        blank_v = nblank; lab_v = nlab; blank0 = nblank0;
    }

    if (lane == u_idx - 1) sLL[b] = ll;
    __syncthreads();
    if (threadIdx.x == 0) {
        float s = 0.f;
        #pragma unroll
        for (int i = 0; i < BB; ++i) s += sLL[i];
        out[0] = -s / BB;
    }
}

extern "C" void kernel_launch(void* const* d_in, const int* in_sizes, int n_in,
                              void* d_out, int out_size, void* d_ws, size_t ws_size,
                              hipStream_t stream) {
    const float* logits     = (const float*)d_in[0];
    const int*   logit_lens = (const int*)d_in[1];
    const int*   y          = (const int*)d_in[2];
    const int*   y_lens     = (const int*)d_in[3];
    float*       out        = (float*)d_out;

    float* lp_blank = (float*)d_ws;                          // B*T*65 floats
    float* lp_label = lp_blank + BB * TT * U1;               // B*T*64 floats

    const int rows = BB * TT * U1;                           // 133120
    k_rowsoftmax<<<rows / 4, 256, 0, stream>>>(logits, y, lp_blank, lp_label);
    k_dp<<<1, 512, 0, stream>>>(lp_blank, lp_label, logit_lens, y_lens, out);
}

// Round 2
// 796.816 us; speedup vs baseline: 1.2491x; 1.2491x over previous
//
#include <hip/hip_runtime.h>
#include <math.h>

#define BB 8
#define TT 256
#define UU 64
#define U1 65
#define VV 1024

#define DD 320                 // number of anti-diagonals stored: t+u in [0, 319]
#define BSTRIDE_BLANK (DD*U1)  // 20800 floats per batch
#define BSTRIDE_LAB   (DD*UU)  // 20480 floats per batch

// ---------------------------------------------------------------------------
// Kernel 1: per (b,t,u) row of 1024 logits, compute logsumexp and emit into
// SKEWED (anti-diagonal-major) layouts so the DP kernel reads contiguously:
//   blankD[b][t+u][u] = logits[b,t,u,0]      - lse
//   labD  [b][t+u][u] = logits[b,t,u,y[b,u]] - lse   (u < UU only)
// One wave (64 lanes) per row; 4 coalesced float4 loads per lane.
// ---------------------------------------------------------------------------
__global__ __launch_bounds__(256) void k_rowsoftmax(
    const float* __restrict__ logits,
    const int* __restrict__ y,
    float* __restrict__ blankD,
    float* __restrict__ labD)
{
    const int lane = threadIdx.x & 63;
    const int r = (blockIdx.x * blockDim.x + threadIdx.x) >> 6;   // row id
    const int b   = r / (TT * U1);
    const int rem = r - b * (TT * U1);
    const int t   = rem / U1;
    const int u   = rem - t * U1;

    const float* row = logits + (size_t)r * VV;

    // Early, independent label-logit load (lane 0 only)
    float labv = 0.f;
    if (lane == 0 && u < UU) {
        int yidx = y[b * UU + u];
        labv = row[yidx];
    }

    const float4* row4 = (const float4*)row;
    float4 x0 = row4[lane];
    float4 x1 = row4[lane + 64];
    float4 x2 = row4[lane + 128];
    float4 x3 = row4[lane + 192];

    // Pass 1: max
    float m = fmaxf(fmaxf(fmaxf(x0.x, x0.y), fmaxf(x0.z, x0.w)),
                    fmaxf(fmaxf(x1.x, x1.y), fmaxf(x1.z, x1.w)));
    m = fmaxf(m, fmaxf(fmaxf(fmaxf(x2.x, x2.y), fmaxf(x2.z, x2.w)),
                       fmaxf(fmaxf(x3.x, x3.y), fmaxf(x3.z, x3.w))));
    #pragma unroll
    for (int off = 32; off; off >>= 1)
        m = fmaxf(m, __shfl_xor(m, off));

    // Pass 2: sum of exp(x - m)
    float s = __expf(x0.x - m) + __expf(x0.y - m) + __expf(x0.z - m) + __expf(x0.w - m)
            + __expf(x1.x - m) + __expf(x1.y - m) + __expf(x1.z - m) + __expf(x1.w - m)
            + __expf(x2.x - m) + __expf(x2.y - m) + __expf(x2.z - m) + __expf(x2.w - m)
            + __expf(x3.x - m) + __expf(x3.y - m) + __expf(x3.z - m) + __expf(x3.w - m);
    #pragma unroll
    for (int off = 32; off; off >>= 1)
        s += __shfl_xor(s, off);

    const float lse = m + __logf(s);

    if (lane == 0) {
        const int d = t + u;
        blankD[b * BSTRIDE_BLANK + d * U1 + u] = x0.x - lse;
        if (u < UU)
            labD[b * BSTRIDE_LAB + d * UU + u] = labv - lse;
    }
}

// ---------------------------------------------------------------------------
// Kernel 2: anti-diagonal wavefront DP. One block (one wave) per batch.
// Lane l handles column u = l+1; lane's loads for diagonal d are CONTIGUOUS
// in the skewed layout:
//   blank[t-1][u]  (t+u=d)  -> blankD[(d-1)*65 + u]
//   label[t][u-1]  (t+u=d)  -> labD  [(d-1)*64 + lane]
// Left neighbor via __shfl_up(cur, 1); u=0 column carried by lane 0.
// ---------------------------------------------------------------------------
__device__ __forceinline__ float logaddexpf_(float a, float b) {
    float m = fmaxf(a, b);
    float d = fabsf(a - b);
    return m + log1pf(__expf(-d));
}

__global__ __launch_bounds__(64) void k_dp(
    const float* __restrict__ blankD,
    const float* __restrict__ labD,
    const int* __restrict__ logit_lens,
    const int* __restrict__ y_lens,
    float* __restrict__ out)
{
    const int lane = threadIdx.x;
    const int b    = blockIdx.x;

    const float* pb = blankD + b * BSTRIDE_BLANK;   // [320][65] skewed
    const float* pl = labD   + b * BSTRIDE_LAB;     // [320][64] skewed

    const int t_idx = logit_lens[b] - 1;        // in [127,255]
    const int u_idx = y_lens[b];                // in [32,64]
    const int u     = lane + 1;
    const int dmax  = t_idx + u_idx;            // final capture diagonal

    // alpha0[u] = inclusive prefix sum of label[0][0..lane] = labD[lane*64+lane]
    float cur = pl[lane * (UU + 1)];
    #pragma unroll
    for (int off = 1; off < 64; off <<= 1) {
        float tv = __shfl_up(cur, off);
        if (lane >= off) cur += tv;
    }

    float a0 = 0.f;                              // lane0: alpha[t][0] running value
    const float fin_blank = pb[dmax * U1 + u_idx];
    float ll = 0.f;

    // Prefetch for d = 2 (diagonal d reads skewed row d-1)
    float blank_v = pb[1 * U1 + u];
    float lab_v   = pl[1 * UU + lane];
    float blank0  = pb[0];                       // blank[d-2=0][0] at d=2

    for (int d = 2; d <= dmax; ++d) {
        // Prefetch diagonal d+1 (row d) — addresses independent of recurrence
        const float nblank  = pb[d * U1 + u];
        const float nlab    = pl[d * UU + lane];
        const float nblank0 = pb[(d - 1) * U1]; // blank[d-1][0] for next iter

        // u=0 column carry: a0 becomes alpha[d-1][0]
        a0 += blank0;

        float left = __shfl_up(cur, 1);
        if (lane == 0) left = a0;

        const int t = d - u;
        if (t >= 1 && t <= TT - 1)
            cur = logaddexpf_(cur + blank_v, left + lab_v);

        if (t == t_idx && lane == u_idx - 1)
            ll = cur + fin_blank;

        blank_v = nblank; lab_v = nlab; blank0 = nblank0;
    }

    if (lane == u_idx - 1)
        atomicAdd(out, -ll * (1.0f / BB));
}

extern "C" void kernel_launch(void* const* d_in, const int* in_sizes, int n_in,
                              void* d_out, int out_size, void* d_ws, size_t ws_size,
                              hipStream_t stream) {
    const float* logits     = (const float*)d_in[0];
    const int*   logit_lens = (const int*)d_in[1];
    const int*   y          = (const int*)d_in[2];
    const int*   y_lens     = (const int*)d_in[3];
    float*       out        = (float*)d_out;

    float* blankD = (float*)d_ws;                         // B*320*65 floats
    float* labD   = blankD + BB * BSTRIDE_BLANK;          // B*320*64 floats

    hipMemsetAsync(out, 0, sizeof(float) * out_size, stream);

    const int rows = BB * TT * U1;                        // 133120
    k_rowsoftmax<<<rows / 4, 256, 0, stream>>>(logits, y, blankD, labD);
    k_dp<<<BB, 64, 0, stream>>>(blankD, labD, logit_lens, y_lens, out);
}